// Round 4
// baseline (183.381 us; speedup 1.0000x reference)
//
#include <hip/hip_runtime.h>

// MultiScaleRoIAlign: B=2, Nb=256 (R=512 rois), C=256, PH=PW=7, GRID=2.
// R8 = R7 resubmitted (previous bench died on container acquisition, not on
// the kernel; audit found no hang/race/OOB vector in the two changes).
// R7: break the per-round vmcnt drain. R4/R6 both plateau at ~70us/dispatch
// with no pipe >26% busy -> latency-serialized. __syncthreads() emits
// s_waitcnt vmcnt(0) before s_barrier, draining the prefetch at every
// barrier (in-flight window ~= compute ~300cy vs 500-900cy load latency).
// Fix (m201/T3-T4 idiom, plain HIP):
//   - raw barriers: s_waitcnt lgkmcnt(0) + __builtin_amdgcn_s_barrier()
//     (LDS visibility kept; vmcnt rides across barriers)
//   - 2-deep register prefetch (bufA/bufB, static indexing): loads for
//     round r+2 issue in round r -> ~2 rounds in flight, latency covered.
// Everything else identical to R6 (verified): float4 channel-interleaved
// slab, b128 DS ops, kmax-adaptive staging, quad-split compute.

#define PHW 49
#define NCHUNK 8
#define CH 32            // channels per block (8 rounds of 4)
#define PSIZE 1024       // float4 slots; psize provably <= ~900

#define BARRIER_KEEP_VMCNT()                                   \
    do {                                                       \
        asm volatile("s_waitcnt lgkmcnt(0)" ::: "memory");     \
        __builtin_amdgcn_s_barrier();                          \
    } while (0)

__global__ __launch_bounds__(256) void msroi_kernel(
    const float* __restrict__ f0, const float* __restrict__ f1,
    const float* __restrict__ f2, const float* __restrict__ f3,
    const float* __restrict__ boxes, float* __restrict__ out)
{
    const int C = 256, Nb = 256;
    const int r = blockIdx.x;            // roi 0..511
    const int chunk = blockIdx.y;        // 0..7
    const int tid = threadIdx.x;         // 0..255
    const int b = r / Nb;

    const int bin = tid >> 2;            // 0..63 (active if < 49)
    const int q   = tid & 3;             // 2x2 sample index within bin
    const bool active = bin < PHW;

    // ---- per-roi params (uniform) ----
    const float x1b = boxes[r * 4 + 0];
    const float y1b = boxes[r * 4 + 1];
    const float x2b = boxes[r * 4 + 2];
    const float y2b = boxes[r * 4 + 3];
    const float area = fmaxf((x2b - x1b) * (y2b - y1b), 0.0f);
    const float s = sqrtf(area);
    float lv = floorf(4.0f + log2f(s / 224.0f + 1e-6f));
    lv = fminf(fmaxf(lv, 2.0f), 5.0f);
    const int lvl = (int)lv - 2;

    const float* feat;
    int H, W;
    float scale;
    switch (lvl) {
        case 0:  feat = f0; H = 200; W = 200; scale = 0.25f;    break;
        case 1:  feat = f1; H = 100; W = 100; scale = 0.125f;   break;
        case 2:  feat = f2; H = 50;  W = 50;  scale = 0.0625f;  break;
        default: feat = f3; H = 25;  W = 25;  scale = 0.03125f; break;
    }
    const int HW = H * W;

    const float x1 = x1b * scale, y1 = y1b * scale;
    const float x2 = x2b * scale, y2 = y2b * scale;
    const float roi_w = fmaxf(x2 - x1, 1.0f);
    const float roi_h = fmaxf(y2 - y1, 1.0f);
    const float bin_w = roi_w * (1.0f / 7.0f);
    const float bin_h = roi_h * (1.0f / 7.0f);

    // ---- patch bounds (uniform): samples at gy,gx in {0.25 .. 6.75} ----
    const float ys0 = fminf(fmaxf(y1 + 0.25f * bin_h, 0.0f), (float)(H - 1));
    const float ys1 = fminf(fmaxf(y1 + 6.75f * bin_h, 0.0f), (float)(H - 1));
    const float xs0 = fminf(fmaxf(x1 + 0.25f * bin_w, 0.0f), (float)(W - 1));
    const float xs1 = fminf(fmaxf(x1 + 6.75f * bin_w, 0.0f), (float)(W - 1));
    const int row0 = (int)floorf(ys0);
    const int row1 = min((int)floorf(ys1) + 1, H - 1);
    const int col0 = (int)floorf(xs0);
    const int col1 = min((int)floorf(xs1) + 1, W - 1);
    const int prows = row1 - row0 + 1;
    const int pcols = col1 - col0 + 1;
    const int psize = prows * pcols;
    const int wstride = W - pcols;                 // row jump in global plane
    const float inv_pcols = 1.0f / (float)pcols;

    // ---- per-thread staging offsets (loop-invariant): e = tid + k*256 ----
    int goff[4];
#pragma unroll
    for (int k = 0; k < 4; ++k) {
        const int e = tid + k * 256;
        const int ec = min(e, psize - 1);
        const int rr = (int)floorf(((float)ec + 0.5f) * inv_pcols);
        goff[k] = ec + rr * wstride;
    }
    const int kmax = (psize + 255) >> 8;           // 1..4, block-uniform

    // ---- per-lane tap descriptors: sample q of bin -> 4 bilinear taps ----
    int   offs[4];
    float wts[4];
    {
        const int bb = active ? bin : 0;
        const int ph = bb / 7;
        const int pw = bb - ph * 7;
        const int iy = q >> 1, ix = q & 1;
        const float gy = (float)ph + ((float)iy + 0.5f) * 0.5f;
        const float gx = (float)pw + ((float)ix + 0.5f) * 0.5f;
        const float y = y1 + gy * bin_h;
        const float x = x1 + gx * bin_w;
        const bool valid = (y >= -1.0f) && (y <= (float)H) &&
                           (x >= -1.0f) && (x <= (float)W);
        const float yc = fminf(fmaxf(y, 0.0f), (float)(H - 1));
        const float xc = fminf(fmaxf(x, 0.0f), (float)(W - 1));
        const int yl = (int)floorf(yc);
        const int xl = (int)floorf(xc);
        const int yh = min(yl + 1, H - 1);
        const int xh = min(xl + 1, W - 1);
        const float ly = yc - (float)yl;
        const float lx = xc - (float)xl;
        const float hy = 1.0f - ly, hx = 1.0f - lx;
        const float m = valid ? 0.25f : 0.0f;
        const int ry0 = (yl - row0) * pcols, ry1 = (yh - row0) * pcols;
        const int cx0 = xl - col0, cx1 = xh - col0;
        offs[0] = ry0 + cx0;  wts[0] = hy * hx * m;
        offs[1] = ry0 + cx1;  wts[1] = hy * lx * m;
        offs[2] = ry1 + cx0;  wts[2] = ly * hx * m;
        offs[3] = ry1 + cx1;  wts[3] = ly * lx * m;
    }

    // ---- channel-interleaved slab: lds4[e] = {c0[e], c1[e], c2[e], c3[e]} ----
    __shared__ float4 lds4[PSIZE];       // 16 KB

    const int cbase = chunk * CH;
    const float* __restrict__ fch =
        feat + (size_t)(b * C + cbase) * HW + (row0 * W + col0);
    float* __restrict__ outp =
        out + (size_t)r * C * PHW + (size_t)cbase * PHW;

    float4 bufA[4], bufB[4];             // statically indexed -> registers

#define LOADR(BUF, CCV)                                                    \
    do {                                                                   \
        const float* __restrict__ g0 = fch + (size_t)((CCV) + 0) * HW;     \
        const float* __restrict__ g1 = fch + (size_t)((CCV) + 1) * HW;     \
        const float* __restrict__ g2 = fch + (size_t)((CCV) + 2) * HW;     \
        const float* __restrict__ g3 = fch + (size_t)((CCV) + 3) * HW;     \
        _Pragma("unroll")                                                  \
        for (int k = 0; k < 4; ++k) {                                      \
            if (k < kmax) {  /* uniform branch: skip clamped groups */     \
                BUF[k].x = g0[goff[k]];                                    \
                BUF[k].y = g1[goff[k]];                                    \
                BUF[k].z = g2[goff[k]];                                    \
                BUF[k].w = g3[goff[k]];                                    \
            }                                                              \
        }                                                                  \
    } while (0)

#define WRITELDS(BUF)                                                      \
    do {                                                                   \
        _Pragma("unroll")                                                  \
        for (int k = 0; k < 4; ++k)                                        \
            if (k < kmax) lds4[tid + k * 256] = BUF[k];                    \
    } while (0)

#define COMPUTE(CCV)                                                       \
    do {                                                                   \
        if (active) {                                                      \
            float4 a = make_float4(0.0f, 0.0f, 0.0f, 0.0f);                \
            _Pragma("unroll")                                              \
            for (int j = 0; j < 4; ++j) {                                  \
                const float4 v = lds4[offs[j]];                            \
                a.x += wts[j] * v.x;                                       \
                a.y += wts[j] * v.y;                                       \
                a.z += wts[j] * v.z;                                       \
                a.w += wts[j] * v.w;                                       \
            }                                                              \
            a.x += __shfl_xor(a.x, 1); a.y += __shfl_xor(a.y, 1);          \
            a.z += __shfl_xor(a.z, 1); a.w += __shfl_xor(a.w, 1);          \
            a.x += __shfl_xor(a.x, 2); a.y += __shfl_xor(a.y, 2);          \
            a.z += __shfl_xor(a.z, 2); a.w += __shfl_xor(a.w, 2);          \
            const float vout = (q == 0) ? a.x : (q == 1) ? a.y             \
                             : (q == 2) ? a.z : a.w;                       \
            outp[(size_t)((CCV) + q) * PHW + bin] = vout;                  \
        }                                                                  \
    } while (0)

    // 2-deep prologue: rounds 0 and 1 in flight before the loop
    LOADR(bufA, 0);
    LOADR(bufB, 4);

#pragma unroll
    for (int c = 0; c < CH; c += 8) {
        // ---- round A (channels c..c+3) ----
        BARRIER_KEEP_VMCNT();            // WAR: prev round's LDS reads done
        WRITELDS(bufA);                  // auto-waitcnt on bufA's loads only
        if (c + 8 < CH) LOADR(bufA, c + 8);   // prefetch 2 rounds ahead
        BARRIER_KEEP_VMCNT();            // staged data visible
        COMPUTE(c);

        // ---- round B (channels c+4..c+7) ----
        BARRIER_KEEP_VMCNT();
        WRITELDS(bufB);
        if (c + 12 < CH) LOADR(bufB, c + 12);
        BARRIER_KEEP_VMCNT();
        COMPUTE(c + 4);
    }
#undef LOADR
#undef WRITELDS
#undef COMPUTE
}

extern "C" void kernel_launch(void* const* d_in, const int* in_sizes, int n_in,
                              void* d_out, int out_size, void* d_ws, size_t ws_size,
                              hipStream_t stream) {
    const float* f0 = (const float*)d_in[0];
    const float* f1 = (const float*)d_in[1];
    const float* f2 = (const float*)d_in[2];
    const float* f3 = (const float*)d_in[3];
    const float* boxes = (const float*)d_in[4];
    float* out = (float*)d_out;

    const int R = in_sizes[4] / 4;   // 512 rois
    dim3 grid(R, NCHUNK);
    msroi_kernel<<<grid, 256, 0, stream>>>(f0, f1, f2, f3, boxes, out);
}

// Round 5
// 180.126 us; speedup vs baseline: 1.0181x; 1.0181x over previous
//
#include <hip/hip_runtime.h>

// MultiScaleRoIAlign: B=2, Nb=256 (R=512 rois), C=256, PH=PW=7, GRID=2.
// R9: R8's VGPR_Count=32 proves the 2-deep register pipeline never installed
// (bufA+bufB alone need 32 VGPRs) -- the branchy `if (k<kmax)` loads let the
// compiler collapse load->wait->write serially. All rounds so far benched the
// SAME effective schedule. Fix:
//   - kmax eliminated: loads AND LDS writes unconditional straight-line
//     (clamped goff => extra slots hold garbage that offs[]<psize never reads)
//   - double-buffered LDS (2 x 16 KB): ONE raw barrier per round (was 2);
//     segment = {COMPUTE(cur); WRITELDS(nxt,buf); LOADR(buf,+16ch); BARRIER}
//   - raw lgkmcnt(0)-only barriers: vmcnt rides across (T3/T4 idiom)
// Install check: VGPR >= ~56, LDS_Block_Size = 32768. If VGPR ~32 again ->
// compiler defeated it again -> inline-asm loads next, not schedule tweaks.

#define PHW 49
#define NCHUNK 8
#define CH 32            // channels per block (8 rounds of 4)
#define PSIZE 1024       // float4 slots per slab; psize provably <= ~900

#define BARRIER_KEEP_VMCNT()                                   \
    do {                                                       \
        asm volatile("s_waitcnt lgkmcnt(0)" ::: "memory");     \
        __builtin_amdgcn_s_barrier();                          \
    } while (0)

__global__ __launch_bounds__(256, 5) void msroi_kernel(
    const float* __restrict__ f0, const float* __restrict__ f1,
    const float* __restrict__ f2, const float* __restrict__ f3,
    const float* __restrict__ boxes, float* __restrict__ out)
{
    const int C = 256, Nb = 256;
    const int r = blockIdx.x;            // roi 0..511
    const int chunk = blockIdx.y;        // 0..7
    const int tid = threadIdx.x;         // 0..255
    const int b = r / Nb;

    const int bin = tid >> 2;            // 0..63 (active if < 49)
    const int q   = tid & 3;             // 2x2 sample index within bin
    const bool active = bin < PHW;

    // ---- per-roi params (uniform) ----
    const float x1b = boxes[r * 4 + 0];
    const float y1b = boxes[r * 4 + 1];
    const float x2b = boxes[r * 4 + 2];
    const float y2b = boxes[r * 4 + 3];
    const float area = fmaxf((x2b - x1b) * (y2b - y1b), 0.0f);
    const float s = sqrtf(area);
    float lv = floorf(4.0f + log2f(s / 224.0f + 1e-6f));
    lv = fminf(fmaxf(lv, 2.0f), 5.0f);
    const int lvl = (int)lv - 2;

    const float* feat;
    int H, W;
    float scale;
    switch (lvl) {
        case 0:  feat = f0; H = 200; W = 200; scale = 0.25f;    break;
        case 1:  feat = f1; H = 100; W = 100; scale = 0.125f;   break;
        case 2:  feat = f2; H = 50;  W = 50;  scale = 0.0625f;  break;
        default: feat = f3; H = 25;  W = 25;  scale = 0.03125f; break;
    }
    const int HW = H * W;

    const float x1 = x1b * scale, y1 = y1b * scale;
    const float x2 = x2b * scale, y2 = y2b * scale;
    const float roi_w = fmaxf(x2 - x1, 1.0f);
    const float roi_h = fmaxf(y2 - y1, 1.0f);
    const float bin_w = roi_w * (1.0f / 7.0f);
    const float bin_h = roi_h * (1.0f / 7.0f);

    // ---- patch bounds (uniform): samples at gy,gx in {0.25 .. 6.75} ----
    const float ys0 = fminf(fmaxf(y1 + 0.25f * bin_h, 0.0f), (float)(H - 1));
    const float ys1 = fminf(fmaxf(y1 + 6.75f * bin_h, 0.0f), (float)(H - 1));
    const float xs0 = fminf(fmaxf(x1 + 0.25f * bin_w, 0.0f), (float)(W - 1));
    const float xs1 = fminf(fmaxf(x1 + 6.75f * bin_w, 0.0f), (float)(W - 1));
    const int row0 = (int)floorf(ys0);
    const int row1 = min((int)floorf(ys1) + 1, H - 1);
    const int col0 = (int)floorf(xs0);
    const int col1 = min((int)floorf(xs1) + 1, W - 1);
    const int prows = row1 - row0 + 1;
    const int pcols = col1 - col0 + 1;
    const int psize = prows * pcols;
    const int wstride = W - pcols;                 // row jump in global plane
    const float inv_pcols = 1.0f / (float)pcols;

    // ---- per-thread staging offsets (loop-invariant): e = tid + k*256 ----
    // Clamped: e >= psize reads the last patch element (valid address).
    int goff[4];
#pragma unroll
    for (int k = 0; k < 4; ++k) {
        const int e = tid + k * 256;
        const int ec = min(e, psize - 1);
        const int rr = (int)floorf(((float)ec + 0.5f) * inv_pcols);
        goff[k] = ec + rr * wstride;
    }

    // ---- per-lane tap descriptors: sample q of bin -> 4 bilinear taps ----
    int   offs[4];
    float wts[4];
    {
        const int bb = active ? bin : 0;
        const int ph = bb / 7;
        const int pw = bb - ph * 7;
        const int iy = q >> 1, ix = q & 1;
        const float gy = (float)ph + ((float)iy + 0.5f) * 0.5f;
        const float gx = (float)pw + ((float)ix + 0.5f) * 0.5f;
        const float y = y1 + gy * bin_h;
        const float x = x1 + gx * bin_w;
        const bool valid = (y >= -1.0f) && (y <= (float)H) &&
                           (x >= -1.0f) && (x <= (float)W);
        const float yc = fminf(fmaxf(y, 0.0f), (float)(H - 1));
        const float xc = fminf(fmaxf(x, 0.0f), (float)(W - 1));
        const int yl = (int)floorf(yc);
        const int xl = (int)floorf(xc);
        const int yh = min(yl + 1, H - 1);
        const int xh = min(xl + 1, W - 1);
        const float ly = yc - (float)yl;
        const float lx = xc - (float)xl;
        const float hy = 1.0f - ly, hx = 1.0f - lx;
        const float m = valid ? 0.25f : 0.0f;
        const int ry0 = (yl - row0) * pcols, ry1 = (yh - row0) * pcols;
        const int cx0 = xl - col0, cx1 = xh - col0;
        offs[0] = ry0 + cx0;  wts[0] = hy * hx * m;
        offs[1] = ry0 + cx1;  wts[1] = hy * lx * m;
        offs[2] = ry1 + cx0;  wts[2] = ly * hx * m;
        offs[3] = ry1 + cx1;  wts[3] = ly * lx * m;
    }

    // ---- double-buffered channel-interleaved slabs (32 KB) ----
    __shared__ float4 lds4[2][PSIZE];

    const int cbase = chunk * CH;
    const float* __restrict__ fch =
        feat + (size_t)(b * C + cbase) * HW + (row0 * W + col0);
    float* __restrict__ outp =
        out + (size_t)r * C * PHW + (size_t)cbase * PHW;

    float4 bufA[4], bufB[4];             // statically indexed -> registers

#define LOADR(BUF, CCV)                                                    \
    do {                                                                   \
        const float* __restrict__ g0 = fch + (size_t)((CCV) + 0) * HW;     \
        const float* __restrict__ g1 = fch + (size_t)((CCV) + 1) * HW;     \
        const float* __restrict__ g2 = fch + (size_t)((CCV) + 2) * HW;     \
        const float* __restrict__ g3 = fch + (size_t)((CCV) + 3) * HW;     \
        _Pragma("unroll")                                                  \
        for (int k = 0; k < 4; ++k) {                                      \
            BUF[k].x = g0[goff[k]];                                        \
            BUF[k].y = g1[goff[k]];                                        \
            BUF[k].z = g2[goff[k]];                                        \
            BUF[k].w = g3[goff[k]];                                        \
        }                                                                  \
    } while (0)

#define WRITELDS(SL, BUF)                                                  \
    do {                                                                   \
        _Pragma("unroll")                                                  \
        for (int k = 0; k < 4; ++k)                                        \
            lds4[SL][tid + k * 256] = BUF[k];                              \
    } while (0)

#define COMPUTE(SL, CCV)                                                   \
    do {                                                                   \
        if (active) {                                                      \
            float4 a = make_float4(0.0f, 0.0f, 0.0f, 0.0f);                \
            _Pragma("unroll")                                              \
            for (int j = 0; j < 4; ++j) {                                  \
                const float4 v = lds4[SL][offs[j]];                        \
                a.x += wts[j] * v.x;                                       \
                a.y += wts[j] * v.y;                                       \
                a.z += wts[j] * v.z;                                       \
                a.w += wts[j] * v.w;                                       \
            }                                                              \
            a.x += __shfl_xor(a.x, 1); a.y += __shfl_xor(a.y, 1);          \
            a.z += __shfl_xor(a.z, 1); a.w += __shfl_xor(a.w, 1);          \
            a.x += __shfl_xor(a.x, 2); a.y += __shfl_xor(a.y, 2);          \
            a.z += __shfl_xor(a.z, 2); a.w += __shfl_xor(a.w, 2);          \
            const float vout = (q == 0) ? a.x : (q == 1) ? a.y             \
                             : (q == 2) ? a.z : a.w;                       \
            outp[(size_t)((CCV) + q) * PHW + bin] = vout;                  \
        }                                                                  \
    } while (0)

    // Prologue: 2-deep register prefetch + first slab staged.
    LOADR(bufA, 0);
    LOADR(bufB, 4);
    WRITELDS(0, bufA);                   // vmcnt wait covers bufA only
    LOADR(bufA, 8);
    BARRIER_KEEP_VMCNT();                // slab0 visible

    // Segment i: COMPUTE(slab[i&1], 4i); stage slab[(i+1)&1] <- buf(i&1?A:B)
    //            with channels 4(i+1); prefetch channels 4(i+3) into same buf.
    // Safety: slab written at segment i was last read at segment i-2; two
    // barriers intervene, so all waves' reads retired. Loads have 2 segments
    // (~2 round-times) of slack before their vmcnt wait at WRITELDS.
#pragma unroll
    for (int i = 0; i < 8; ++i) {
        const int cur = i & 1, nxt = cur ^ 1;
        COMPUTE(cur, i * 4);
        if (i < 7) {
            if (i & 1) {
                WRITELDS(nxt, bufA);
                if (i + 3 < 8) LOADR(bufA, (i + 3) * 4);
            } else {
                WRITELDS(nxt, bufB);
                if (i + 3 < 8) LOADR(bufB, (i + 3) * 4);
            }
        }
        BARRIER_KEEP_VMCNT();
    }
#undef LOADR
#undef WRITELDS
#undef COMPUTE
}

extern "C" void kernel_launch(void* const* d_in, const int* in_sizes, int n_in,
                              void* d_out, int out_size, void* d_ws, size_t ws_size,
                              hipStream_t stream) {
    const float* f0 = (const float*)d_in[0];
    const float* f1 = (const float*)d_in[1];
    const float* f2 = (const float*)d_in[2];
    const float* f3 = (const float*)d_in[3];
    const float* boxes = (const float*)d_in[4];
    float* out = (float*)d_out;

    const int R = in_sizes[4] / 4;   // 512 rois
    dim3 grid(R, NCHUNK);
    msroi_kernel<<<grid, 256, 0, stream>>>(f0, f1, f2, f3, boxes, out);
}